// Round 8
// baseline (250.109 us; speedup 1.0000x reference)
//
#include <hip/hip_runtime.h>
#include <hip/hip_fp16.h>

// GCN 2-layer forward on MI355X — R18: feature-quad gather lanes.
// Aggregation lane = (edge-quarter q=0..3, feature-quad f4=0..15); each lane
// gathers 8 B (half4) of a row -> 16 lanes/row, 16 edges/iter with
// 1 int4 + 4 gathers per lane = 5 VMEM instr / 16 edges (was 10), half the
// address VALU. Accumulators are 4 NAMED scalars (rule #20: no local arrays).
// Cross-quarter reduce = shfl ^16 then ^32. k_agg2 additionally guards
// gathers with f4<10 (40 features) -> drops the 37.5% dead-column traffic.
// Kept: MFMA GEMM1 (hi/lo fp16, fp32-grade), scalar GEMM2 (proven VGPR-32),
// x8-padded esrc segments, deg from k_bucket, unroll-1 pins.
// Pipeline: hist -> scan(+W1t) -> scatter -> bucket(deg) -> gemm1m -> agg1mm -> agg2
// d_in: [0]=x (N*128 f32), [1]=edge_index (2*E i32), [2]=W1 (128*64),
//       [3]=b1 (64), [4]=W2 (64*40), [5]=b2 (40)
// d_out: N*40 f32

#define FIN 128
#define H1  64
#define C2  40
#define GP  64            // padded row stride (halves) for g => 128 B lines
#define TILE 8192         // edges per hist/scatter tile
#define BCAP 7168         // padded bucket capacity (mean 4096 + <=1792 pad)
#define WTS 132           // padded W1t row stride (halves): bank-conflict-free

typedef _Float16 half4_t __attribute__((ext_vector_type(4)));
typedef float float4_t __attribute__((ext_vector_type(4)));

__device__ __forceinline__ float2 h2f(unsigned u) {
    union { unsigned v; __half2 h; } c; c.v = u;
    return __half22float2(c.h);
}

// ---------- histogram: per-bucket counts only (LDS atomics) ----------
__global__ __launch_bounds__(256) void k_hist(const int* __restrict__ col, int E,
                                              int* __restrict__ bucketCnt, int NB) {
    __shared__ int lh[512];
    int t = threadIdx.x;
    for (int i = t; i < NB; i += 256) lh[i] = 0;
    __syncthreads();
    int base = blockIdx.x * TILE;
    int cnt = min(TILE, E - base);
    for (int i = t; i < cnt; i += 256) atomicAdd(&lh[col[base + i] >> 8], 1);
    __syncthreads();
    for (int b = t; b < NB; b += 256) if (lh[b]) atomicAdd(&bucketCnt[b], lh[b]);
}

// ---------- scan over NB buckets; sentinel rows; W1 -> hi/lo fp16 planes ----------
__global__ __launch_bounds__(512) void k_scan(const int* __restrict__ bucketCnt,
                                              int* __restrict__ rawBase,
                                              int* __restrict__ padBase,
                                              int* __restrict__ gcursor,
                                              __half* __restrict__ h1,
                                              __half* __restrict__ g,
                                              const float* __restrict__ W1,
                                              _Float16* __restrict__ W1th,
                                              _Float16* __restrict__ W1tl,
                                              int NB, int N) {
    __shared__ int sr[512], sp[512];
    int t = threadIdx.x;
    int c = (t < NB) ? bucketCnt[t] : 0;
    int p = (t < NB) ? (((c + 7) & ~7) + 2048) : 0;   // room for per-dest x8 pad
    sr[t] = c; sp[t] = p;
    __syncthreads();
    for (int off = 1; off < 512; off <<= 1) {
        int a = (t >= off) ? sr[t - off] : 0;
        int b = (t >= off) ? sp[t - off] : 0;
        __syncthreads();
        sr[t] += a; sp[t] += b;
        __syncthreads();
    }
    if (t <= NB) {
        rawBase[t] = sr[t] - ((t < NB) ? c : 0);
        padBase[t] = sp[t] - ((t < NB) ? p : 0);
        if (t < NB) gcursor[t] = sr[t] - c;
    }
    // sentinel rows: pad entries reference src == N and must contribute 0
    if (t < 32) ((unsigned*)(h1 + (size_t)N * H1))[t] = 0u;
    else if (t < 64) ((unsigned*)(g + (size_t)N * GP))[t - 32] = 0u;
    // W1 (fp32 [k][o]) -> transposed padded hi/lo fp16 planes [o][WTS]
    for (int i = t; i < FIN * H1; i += 512) {
        int o = i >> 7, k = i & 127;
        float wv = W1[k * H1 + o];
        _Float16 hi = (_Float16)wv;
        W1th[o * WTS + k] = hi;
        W1tl[o * WTS + k] = (_Float16)(wv - (float)hi);
    }
}

// ---------- scatter into bucket-contiguous chunks (packed pairs) ----------
// packed: bits 0..23 = src row, bits 24..31 = dest low 8
__global__ __launch_bounds__(512) void k_scatter(const int* __restrict__ row,
                                                 const int* __restrict__ col,
                                                 int* __restrict__ gcursor,
                                                 int* __restrict__ pairs,
                                                 int E, int NB) {
    __shared__ int2 stage[TILE];         // 64 KB
    __shared__ int lcnt[512];
    __shared__ int lex[512];
    __shared__ int gbase[512];
    int t = threadIdx.x, tile = blockIdx.x;
    int base = tile * TILE;
    int cnt = min(TILE, E - base);

    lcnt[t] = 0;
    __syncthreads();
    for (int i = t; i < cnt; i += 512) atomicAdd(&lcnt[col[base + i] >> 8], 1);
    __syncthreads();

    int myc = lcnt[t];
    lex[t] = myc;
    __syncthreads();
    for (int off = 1; off < 512; off <<= 1) {
        int u = (t >= off) ? lex[t - off] : 0;
        __syncthreads();
        lex[t] += u;
        __syncthreads();
    }
    int ex = lex[t] - myc;
    __syncthreads();
    lex[t] = ex;
    lcnt[t] = ex;                         // local cursor
    if (t < NB && myc > 0) gbase[t] = atomicAdd(&gcursor[t], myc);
    __syncthreads();

    for (int i = t; i < cnt; i += 512) {
        int r = row[base + i], c = col[base + i];
        int lpos = atomicAdd(&lcnt[c >> 8], 1);
        stage[lpos] = make_int2(r, c);
    }
    __syncthreads();

    for (int i = t; i < cnt; i += 512) {
        int2 p = stage[i];
        int b = p.y >> 8;
        pairs[gbase[b] + (i - lex[b])] = p.x | ((p.y & 255) << 24);
    }
}

// ---------- per-bucket final sort by dest; x8-padded esrc segments; deg ----------
__global__ __launch_bounds__(512) void k_bucket(const int* __restrict__ pairs,
                                                const int* __restrict__ rawBase,
                                                const int* __restrict__ padBase,
                                                int* __restrict__ rowptr,
                                                int* __restrict__ deg,
                                                int* __restrict__ esrc,
                                                int N, int NB) {
    __shared__ int dcnt[256];
    __shared__ int sr[256], sp[256];
    __shared__ int cur[256];
    __shared__ int outbuf[BCAP];         // 28 KB
    int t = threadIdx.x, b = blockIdx.x;
    int d0 = b << 8;
    int nd = min(256, N - d0);
    int bstart = rawBase[b];
    int cnt = rawBase[b + 1] - bstart;
    int pstart = padBase[b];

    if (t < 256) dcnt[t] = 0;
    __syncthreads();
    for (int i = t; i < cnt; i += 512) {
        unsigned p = (unsigned)pairs[bstart + i];
        atomicAdd(&dcnt[p >> 24], 1);
    }
    __syncthreads();

    int myc = 0, myp = 0;
    if (t < 256) {
        myc = dcnt[t];
        myp = (myc + 7) & ~7;
        sr[t] = myc; sp[t] = myp;
    }
    __syncthreads();
    for (int off = 1; off < 256; off <<= 1) {
        int a = 0, c2 = 0;
        if (t < 256 && t >= off) { a = sr[t - off]; c2 = sp[t - off]; }
        __syncthreads();
        if (t < 256) { sr[t] += a; sp[t] += c2; }
        __syncthreads();
    }
    if (t < 256) {
        int pex = sp[t] - myp;
        cur[t] = pex;
        if (t < nd) {
            rowptr[d0 + t] = pstart + pex;
            deg[d0 + t] = myc;            // degree for free
        }
    }
    __syncthreads();
    int pcnt = sp[255];

    if (pcnt <= BCAP) {
        for (int i = t; i < cnt; i += 512) {
            unsigned p = (unsigned)pairs[bstart + i];
            int lpos = atomicAdd(&cur[p >> 24], 1);
            outbuf[lpos] = (int)(p & 0xFFFFFF);
        }
        __syncthreads();
        if (t < 256) {
            int pex = sp[t] - myp;
            for (int j = myc; j < myp; ++j) outbuf[pex + j] = N;   // sentinel pad
        }
        __syncthreads();
        for (int i = t; i < pcnt; i += 512) esrc[pstart + i] = outbuf[i];
    } else {
        for (int i = t; i < cnt; i += 512) {
            unsigned p = (unsigned)pairs[bstart + i];
            int lpos = atomicAdd(&cur[p >> 24], 1);
            esrc[pstart + lpos] = (int)(p & 0xFFFFFF);
        }
        __syncthreads();
        if (t < 256) {
            int pex = sp[t] - myp;
            for (int j = myc; j < myp; ++j) esrc[pstart + pex + j] = N;
        }
    }
}

// ---------- GEMM1 via MFMA: h1' = (x@W1)*dinv, hi/lo fp16 split ----------
__global__ __launch_bounds__(256) void k_gemm1m(const float* __restrict__ x,
                                                const _Float16* __restrict__ W1th,
                                                const _Float16* __restrict__ W1tl,
                                                const int* __restrict__ deg,
                                                __half* __restrict__ h1, int N) {
    __shared__ alignas(16) _Float16 Wh[H1 * WTS];   // 16.5 KB
    __shared__ alignas(16) _Float16 Wl[H1 * WTS];   // 16.5 KB
    int t = threadIdx.x;

    {   // stage both planes: 8448 halves = 1056 uint4 each
        const uint4* sh = (const uint4*)W1th;
        const uint4* sl = (const uint4*)W1tl;
        uint4* dh = (uint4*)Wh;
        uint4* dl = (uint4*)Wl;
        for (int i = t; i < (H1 * WTS) / 8; i += 256) { dh[i] = sh[i]; dl[i] = sl[i]; }
    }

    int wv = t >> 6, l = t & 63;
    int col = l & 15;             // node within 16-tile (and A-row lane index)
    int krow = l >> 4;            // 0..3
    int node = blockIdx.x * 64 + wv * 16 + col;
    int nodec = min(node, N - 1);

    // B fragments from x: lane holds x[node][kt*16 + krow*4 + 0..3]
    half4_t bh[8], bl[8];
    const float4* xr = (const float4*)(x + (size_t)nodec * FIN);
#pragma unroll
    for (int kt = 0; kt < 8; ++kt) {
        float4 v = xr[kt * 4 + krow];
        half4_t hi, lo;
        hi[0] = (_Float16)v.x; lo[0] = (_Float16)(v.x - (float)hi[0]);
        hi[1] = (_Float16)v.y; lo[1] = (_Float16)(v.y - (float)hi[1]);
        hi[2] = (_Float16)v.z; lo[2] = (_Float16)(v.z - (float)hi[2]);
        hi[3] = (_Float16)v.w; lo[3] = (_Float16)(v.w - (float)hi[3]);
        bh[kt] = hi; bl[kt] = lo;
    }
    float dcv = rsqrtf((float)deg[nodec] + 1.0f);
    __syncthreads();

    float4_t acc[4];
#pragma unroll
    for (int ot = 0; ot < 4; ++ot) acc[ot] = (float4_t){0.f, 0.f, 0.f, 0.f};

#pragma unroll
    for (int kt = 0; kt < 8; ++kt) {
#pragma unroll
        for (int ot = 0; ot < 4; ++ot) {
            int aoff = ((ot * 16 + col) * WTS + kt * 16 + krow * 4) >> 2;  // half4 units
            half4_t ah = ((const half4_t*)Wh)[aoff];
            half4_t al = ((const half4_t*)Wl)[aoff];
            acc[ot] = __builtin_amdgcn_mfma_f32_16x16x16f16(ah, bh[kt], acc[ot], 0, 0, 0);
            acc[ot] = __builtin_amdgcn_mfma_f32_16x16x16f16(ah, bl[kt], acc[ot], 0, 0, 0);
            acc[ot] = __builtin_amdgcn_mfma_f32_16x16x16f16(al, bh[kt], acc[ot], 0, 0, 0);
        }
    }

    if (node < N) {
#pragma unroll
        for (int ot = 0; ot < 4; ++ot) {
            union { __half h[4]; uint2 u; } pk;
#pragma unroll
            for (int r = 0; r < 4; ++r) pk.h[r] = __float2half_rn(acc[ot][r] * dcv);
            *(uint2*)&h1[(size_t)node * H1 + ot * 16 + krow * 4] = pk.u;
        }
    }
}

// ---------- fused agg1 + bias + ReLU + GEMM2 per 64-node block ----------
// 512 threads = 8 waves. Aggregation (feature-quad lanes): lane = (q, f4);
// quarter q takes edges i+4q..i+4q+3 via one int4 esrc load; each lane
// gathers uint2 (half4: features 4f4..4f4+3) of pre-scaled h1'. 16 edges/iter
// with 5 VMEM instr. Named scalar accumulators. Reduce = shfl ^16, ^32.
// GEMM2 from LDS in the PROVEN scalar form (VGPR-32 regime).
__global__ __launch_bounds__(512) void k_agg1mm(const int* __restrict__ rowptr,
                                                const int* __restrict__ deg,
                                                const int* __restrict__ esrc,
                                                const __half* __restrict__ h1,
                                                const float* __restrict__ b1,
                                                const float* __restrict__ W2,
                                                __half* __restrict__ g, int N) {
    __shared__ float hs[64][H1 + 4];     // 17 KB: relu(agg1) rows
    __shared__ float Ws[H1 * C2];        // 10 KB, [k][c]
    __shared__ float sdc[64];
    int t = threadIdx.x;
    int node0 = blockIdx.x * 64;

    {   // stage W2: 640 float4
        const float4* W4 = (const float4*)W2;
        float4* Ws4 = (float4*)Ws;
        for (int i = t; i < 640; i += 512) Ws4[i] = W4[i];
    }

    int wv = t >> 6, lane = t & 63;
    int q = lane >> 4;                   // edge-quad selector 0..3
    int f4 = lane & 15;                  // feature-quad index
    float4 b1v = *(const float4*)&b1[4 * f4];
    const uint2* hq = (const uint2*)h1;  // 8-byte units; row stride 16

    // aggregation: 8 nodes per wave, sequential
#pragma unroll 1
    for (int j = 0; j < 8; ++j) {
        int r = wv * 8 + j;
        int node = node0 + r;
        if (node >= N) {
            if (q == 0) *(float4*)&hs[r][4 * f4] = make_float4(0.f, 0.f, 0.f, 0.f);
            if (lane == 0) sdc[r] = 0.f;
            continue;
        }
        int start = rowptr[node], d = deg[node];
        int d8 = (d + 7) & ~7;
        float dc = rsqrtf((float)d + 1.0f);
        float a0 = 0.f, a1 = 0.f, a2 = 0.f, a3 = 0.f;
        int i = 0;
#pragma unroll 1
        for (; i + 16 <= d8; i += 16) {
            int4 s = *(const int4*)&esrc[start + i + q * 4];
            uint2 r0 = hq[s.x * 16 + f4];
            uint2 r1 = hq[s.y * 16 + f4];
            uint2 r2 = hq[s.z * 16 + f4];
            uint2 r3 = hq[s.w * 16 + f4];
            float2 p;
            p = h2f(r0.x); a0 += p.x; a1 += p.y;  p = h2f(r0.y); a2 += p.x; a3 += p.y;
            p = h2f(r1.x); a0 += p.x; a1 += p.y;  p = h2f(r1.y); a2 += p.x; a3 += p.y;
            p = h2f(r2.x); a0 += p.x; a1 += p.y;  p = h2f(r2.y); a2 += p.x; a3 += p.y;
            p = h2f(r3.x); a0 += p.x; a1 += p.y;  p = h2f(r3.y); a2 += p.x; a3 += p.y;
        }
        if (i < d8 && q < 2) {           // one 8-edge chunk: quads 0,1
            int4 s = *(const int4*)&esrc[start + i + q * 4];
            uint2 r0 = hq[s.x * 16 + f4];
            uint2 r1 = hq[s.y * 16 + f4];
            uint2 r2 = hq[s.z * 16 + f4];
            uint2 r3 = hq[s.w * 16 + f4];
            float2 p;
            p = h2f(r0.x); a0 += p.x; a1 += p.y;  p = h2f(r0.y); a2 += p.x; a3 += p.y;
            p = h2f(r1.x); a0 += p.x; a1 += p.y;  p = h2f(r1.y); a2 += p.x; a3 += p.y;
            p = h2f(r2.x); a0 += p.x; a1 += p.y;  p = h2f(r2.y); a2 += p.x; a3 += p.y;
            p = h2f(r3.x); a0 += p.x; a1 += p.y;  p = h2f(r3.y); a2 += p.x; a3 += p.y;
        }
        // reduce across quads (all quads end with full sum)
        a0 += __shfl(a0, lane ^ 16); a1 += __shfl(a1, lane ^ 16);
        a2 += __shfl(a2, lane ^ 16); a3 += __shfl(a3, lane ^ 16);
        a0 += __shfl(a0, lane ^ 32); a1 += __shfl(a1, lane ^ 32);
        a2 += __shfl(a2, lane ^ 32); a3 += __shfl(a3, lane ^ 32);
        if (q == 0) {
            // self-loop (h1' already has one dinv factor) + bias + ReLU
            uint2 sr0 = hq[node * 16 + f4];
            float2 s0 = h2f(sr0.x), s1 = h2f(sr0.y);
            float o0 = fmaxf(fmaf(dc, a0 + s0.x, b1v.x), 0.f);
            float o1 = fmaxf(fmaf(dc, a1 + s0.y, b1v.y), 0.f);
            float o2 = fmaxf(fmaf(dc, a2 + s1.x, b1v.z), 0.f);
            float o3 = fmaxf(fmaf(dc, a3 + s1.y, b1v.w), 0.f);
            *(float4*)&hs[r][4 * f4] = make_float4(o0, o1, o2, o3);
        }
        if (lane == 0) sdc[r] = dc;
    }
    __syncthreads();

    // GEMM2 from LDS: 512 threads = 16 col-groups x 32 row-groups (2 rows each)
    // PROVEN scalar form — do not reintroduce local arrays (rule #20 spill).
    int og = t & 15, ng = t >> 4;
    int o0 = og * 4, n0 = ng * 2;
    int o0c = (o0 <= 36) ? o0 : 36;
    float acc[2][4];
#pragma unroll
    for (int i = 0; i < 2; ++i)
#pragma unroll
        for (int j = 0; j < 4; ++j) acc[i][j] = 0.f;

#pragma unroll 8
    for (int k = 0; k < H1; ++k) {
        float a0 = hs[n0 + 0][k], a1 = hs[n0 + 1][k];
        float4 w = *(const float4*)&Ws[k * C2 + o0c];
        acc[0][0] += a0 * w.x; acc[0][1] += a0 * w.y; acc[0][2] += a0 * w.z; acc[0][3] += a0 * w.w;
        acc[1][0] += a1 * w.x; acc[1][1] += a1 * w.y; acc[1][2] += a1 * w.z; acc[1][3] += a1 * w.w;
    }

    if (o0 < C2) {
#pragma unroll
        for (int i = 0; i < 2; ++i) {
            int node = node0 + n0 + i;
            if (node < N) {
                float dcv = sdc[n0 + i];
                union { __half h[4]; uint2 u; } pk;
                pk.h[0] = __float2half_rn(acc[i][0] * dcv);
                pk.h[1] = __float2half_rn(acc[i][1] * dcv);
                pk.h[2] = __float2half_rn(acc[i][2] * dcv);
                pk.h[3] = __float2half_rn(acc[i][3] * dcv);
                *(uint2*)&g[(size_t)node * GP + o0] = pk.u;
            }
        }
    }
}

// ---------- agg2: wave per node, feature-quad lanes, f4<10 active ----------
__global__ __launch_bounds__(256) void k_agg2(const int* __restrict__ rowptr,
                                              const int* __restrict__ deg,
                                              const int* __restrict__ esrc,
                                              const __half* __restrict__ g,
                                              const float* __restrict__ b2,
                                              float* __restrict__ out, int N) {
    int w = (int)((blockIdx.x * blockDim.x + threadIdx.x) >> 6);
    int lane = threadIdx.x & 63;
    if (w >= N) return;
    int q = lane >> 4;                   // edge-quad selector
    int f4 = lane & 15;                  // feature-quad; active f4<10 (40 feats)
    bool act = f4 < 10;
    const uint2* gq = (const uint2*)g;   // 8-byte units; row stride 16

    int start = rowptr[w], d = deg[w];
    int d8 = (d + 7) & ~7;
    float dc = rsqrtf((float)d + 1.0f);
    float a0 = 0.f, a1 = 0.f, a2 = 0.f, a3 = 0.f;
    if (act) {
        int i = 0;
#pragma unroll 1
        for (; i + 16 <= d8; i += 16) {
            int4 s = *(const int4*)&esrc[start + i + q * 4];
            uint2 r0 = gq[s.x * 16 + f4];
            uint2 r1 = gq[s.y * 16 + f4];
            uint2 r2 = gq[s.z * 16 + f4];
            uint2 r3 = gq[s.w * 16 + f4];
            float2 p;
            p = h2f(r0.x); a0 += p.x; a1 += p.y;  p = h2f(r0.y); a2 += p.x; a3 += p.y;
            p = h2f(r1.x); a0 += p.x; a1 += p.y;  p = h2f(r1.y); a2 += p.x; a3 += p.y;
            p = h2f(r2.x); a0 += p.x; a1 += p.y;  p = h2f(r2.y); a2 += p.x; a3 += p.y;
            p = h2f(r3.x); a0 += p.x; a1 += p.y;  p = h2f(r3.y); a2 += p.x; a3 += p.y;
        }
        if (i < d8 && q < 2) {           // one 8-edge chunk: quads 0,1
            int4 s = *(const int4*)&esrc[start + i + q * 4];
            uint2 r0 = gq[s.x * 16 + f4];
            uint2 r1 = gq[s.y * 16 + f4];
            uint2 r2 = gq[s.z * 16 + f4];
            uint2 r3 = gq[s.w * 16 + f4];
            float2 p;
            p = h2f(r0.x); a0 += p.x; a1 += p.y;  p = h2f(r0.y); a2 += p.x; a3 += p.y;
            p = h2f(r1.x); a0 += p.x; a1 += p.y;  p = h2f(r1.y); a2 += p.x; a3 += p.y;
            p = h2f(r2.x); a0 += p.x; a1 += p.y;  p = h2f(r2.y); a2 += p.x; a3 += p.y;
            p = h2f(r3.x); a0 += p.x; a1 += p.y;  p = h2f(r3.y); a2 += p.x; a3 += p.y;
        }
    }
    // reduce across quads (partners share f4 => activity matches)
    a0 += __shfl(a0, lane ^ 16); a1 += __shfl(a1, lane ^ 16);
    a2 += __shfl(a2, lane ^ 16); a3 += __shfl(a3, lane ^ 16);
    a0 += __shfl(a0, lane ^ 32); a1 += __shfl(a1, lane ^ 32);
    a2 += __shfl(a2, lane ^ 32); a3 += __shfl(a3, lane ^ 32);
    if (q == 0 && act) {
        float4 b2v = *(const float4*)&b2[4 * f4];
        uint2 sr0 = gq[w * 16 + f4];
        float2 s0 = h2f(sr0.x), s1 = h2f(sr0.y);
        float4 o;
        o.x = fmaf(dc, a0 + s0.x, b2v.x);
        o.y = fmaf(dc, a1 + s0.y, b2v.y);
        o.z = fmaf(dc, a2 + s1.x, b2v.z);
        o.w = fmaf(dc, a3 + s1.y, b2v.w);
        *(float4*)&out[(size_t)w * C2 + 4 * f4] = o;
    }
}

extern "C" void kernel_launch(void* const* d_in, const int* in_sizes, int n_in,
                              void* d_out, int out_size, void* d_ws, size_t ws_size,
                              hipStream_t stream) {
    const float* x   = (const float*)d_in[0];
    const int*   ei  = (const int*)d_in[1];
    const float* W1  = (const float*)d_in[2];
    const float* b1  = (const float*)d_in[3];
    const float* W2  = (const float*)d_in[4];
    const float* b2  = (const float*)d_in[5];
    float* out = (float*)d_out;

    const int N = in_sizes[0] / FIN;       // 100000
    const int E = in_sizes[1] / 2;         // 1600000
    const int* row = ei;
    const int* col = ei + E;

    const int NB = (N + 255) >> 8;         // 391 buckets
    const int T  = (E + TILE - 1) / TILE;  // 196 tiles
    const int EP = E + NB * 2048 + 1024;   // padded esrc capacity (x8 pad)

    // workspace layout
    char* ws = (char*)d_ws;
    size_t off = 0;
    int*    bucketCnt = (int*)(ws + off);    off += (size_t)NB * 4;
    int*    rawBase   = (int*)(ws + off);    off += (size_t)(NB + 1) * 4;
    int*    padBase   = (int*)(ws + off);    off += (size_t)(NB + 1) * 4;
    int*    gcursor   = (int*)(ws + off);    off += (size_t)NB * 4;
    int*    deg       = (int*)(ws + off);    off += (size_t)N * 4;
    int*    rowptr    = (int*)(ws + off);    off += (size_t)N * 4;
    int*    pairs     = (int*)(ws + off);    off += (size_t)E * 4;
    off = (off + 15) & ~(size_t)15;
    int*    esrc      = (int*)(ws + off);    off += (size_t)EP * 4;
    off = (off + 15) & ~(size_t)15;
    _Float16* W1th    = (_Float16*)(ws + off); off += (size_t)H1 * WTS * 2;
    off = (off + 15) & ~(size_t)15;
    _Float16* W1tl    = (_Float16*)(ws + off); off += (size_t)H1 * WTS * 2;
    off = (off + 15) & ~(size_t)15;
    __half* h1        = (__half*)(ws + off); off += (size_t)(N + 1) * H1 * 2;
    off = (off + 15) & ~(size_t)15;
    __half* g         = (__half*)(ws + off); off += (size_t)(N + 1) * GP * 2;

    hipMemsetAsync(bucketCnt, 0, (size_t)NB * 4, stream);

    int gblocks = (N + 63) / 64;           // 1563

    // CSR build: bucket histogram -> scan (+W1t planes) -> chunk-claim
    // scatter -> bucket sort (emits deg for free)
    k_hist<<<T, 256, 0, stream>>>(col, E, bucketCnt, NB);
    k_scan<<<1, 512, 0, stream>>>(bucketCnt, rawBase, padBase, gcursor, h1, g,
                                  W1, W1th, W1tl, NB, N);
    k_scatter<<<T, 512, 0, stream>>>(row, col, gcursor, pairs, E, NB);
    k_bucket<<<NB, 512, 0, stream>>>(pairs, rawBase, padBase, rowptr, deg, esrc, N, NB);

    // GEMM1 via MFMA, writes h1' = (x@W1)*dinv (needs deg => after k_bucket)
    k_gemm1m<<<gblocks, 256, 0, stream>>>(x, W1th, W1tl, deg, h1, N);

    // layer 1 aggregation + bias + ReLU + GEMM2 (fused), writes g' = h2*dinv
    k_agg1mm<<<gblocks, 512, 0, stream>>>(rowptr, deg, esrc, h1, b1, W2, g, N);

    // layer 2 aggregation + bias
    k_agg2<<<((size_t)N * 64 + 255) / 256, 256, 0, stream>>>(rowptr, deg, esrc, g, b2, out, N);
}

// Round 9
// 240.944 us; speedup vs baseline: 1.0380x; 1.0380x over previous
//
#include <hip/hip_runtime.h>
#include <hip/hip_fp16.h>

// GCN 2-layer forward on MI355X — R19: R17 agg loops (proven 54 us; R18's
// quad layout regressed — same row-touches, extra shfl hop) + GEMM2 via MFMA.
// Instruction accounting showed GEMM2 = ~8K VALU cyc/block (~half of
// k_agg1mm's VALU, 37.5% wasted on dead columns). Now: aggregation epilogue
// writes hs as hi/lo fp16 LDS planes; W2 pre-transposed to hi/lo planes
// [48][72] in k_scan (cols 40-47 = 0); 12 16x16 tiles over 8 waves, 3 MFMA
// per k-step (fp32-grade, same verified fragment layout as k_gemm1m).
// g cols 48-63 remain unwritten (R17-proven safe: dead lanes discard).
// Kept: MFMA GEMM1, x8-padded esrc, deg from k_bucket, unroll-1 pins.
// Pipeline: hist -> scan(+W1t,W2t) -> scatter -> bucket(deg) -> gemm1m -> agg1mm -> agg2
// d_in: [0]=x (N*128 f32), [1]=edge_index (2*E i32), [2]=W1 (128*64),
//       [3]=b1 (64), [4]=W2 (64*40), [5]=b2 (40)
// d_out: N*40 f32

#define FIN 128
#define H1  64
#define C2  40
#define GP  64            // padded row stride (halves) for g => 128 B lines
#define TILE 8192         // edges per hist/scatter tile
#define BCAP 7168         // padded bucket capacity (mean 4096 + <=1792 pad)
#define WTS 132           // padded W1t row stride (halves): bank-conflict-free
#define W2TS 72           // padded W2t/hs row stride (halves)

typedef _Float16 half4_t __attribute__((ext_vector_type(4)));
typedef float float4_t __attribute__((ext_vector_type(4)));

// ---------- histogram: per-bucket counts only (LDS atomics) ----------
__global__ __launch_bounds__(256) void k_hist(const int* __restrict__ col, int E,
                                              int* __restrict__ bucketCnt, int NB) {
    __shared__ int lh[512];
    int t = threadIdx.x;
    for (int i = t; i < NB; i += 256) lh[i] = 0;
    __syncthreads();
    int base = blockIdx.x * TILE;
    int cnt = min(TILE, E - base);
    for (int i = t; i < cnt; i += 256) atomicAdd(&lh[col[base + i] >> 8], 1);
    __syncthreads();
    for (int b = t; b < NB; b += 256) if (lh[b]) atomicAdd(&bucketCnt[b], lh[b]);
}

// ---------- scan over NB buckets; sentinel rows; W1/W2 -> hi/lo fp16 planes ----------
__global__ __launch_bounds__(512) void k_scan(const int* __restrict__ bucketCnt,
                                              int* __restrict__ rawBase,
                                              int* __restrict__ padBase,
                                              int* __restrict__ gcursor,
                                              __half* __restrict__ h1,
                                              __half* __restrict__ g,
                                              const float* __restrict__ W1,
                                              _Float16* __restrict__ W1th,
                                              _Float16* __restrict__ W1tl,
                                              const float* __restrict__ W2,
                                              _Float16* __restrict__ W2th,
                                              _Float16* __restrict__ W2tl,
                                              int NB, int N) {
    __shared__ int sr[512], sp[512];
    int t = threadIdx.x;
    int c = (t < NB) ? bucketCnt[t] : 0;
    int p = (t < NB) ? (((c + 7) & ~7) + 2048) : 0;   // room for per-dest x8 pad
    sr[t] = c; sp[t] = p;
    __syncthreads();
    for (int off = 1; off < 512; off <<= 1) {
        int a = (t >= off) ? sr[t - off] : 0;
        int b = (t >= off) ? sp[t - off] : 0;
        __syncthreads();
        sr[t] += a; sp[t] += b;
        __syncthreads();
    }
    if (t <= NB) {
        rawBase[t] = sr[t] - ((t < NB) ? c : 0);
        padBase[t] = sp[t] - ((t < NB) ? p : 0);
        if (t < NB) gcursor[t] = sr[t] - c;
    }
    // sentinel rows: pad entries reference src == N and must contribute 0
    if (t < 32) ((unsigned*)(h1 + (size_t)N * H1))[t] = 0u;
    else if (t < 64) ((unsigned*)(g + (size_t)N * GP))[t - 32] = 0u;
    // W1 (fp32 [k][o]) -> transposed padded hi/lo fp16 planes [o][WTS]
    for (int i = t; i < FIN * H1; i += 512) {
        int o = i >> 7, k = i & 127;
        float wv = W1[k * H1 + o];
        _Float16 hi = (_Float16)wv;
        W1th[o * WTS + k] = hi;
        W1tl[o * WTS + k] = (_Float16)(wv - (float)hi);
    }
    // W2 (fp32 [k][c]) -> transposed padded hi/lo fp16 planes [n][W2TS], n<48
    for (int i = t; i < 48 * 64; i += 512) {
        int n = i >> 6, kk = i & 63;
        float wv = (n < C2) ? W2[kk * C2 + n] : 0.f;
        _Float16 hi = (_Float16)wv;
        W2th[n * W2TS + kk] = hi;
        W2tl[n * W2TS + kk] = (_Float16)(wv - (float)hi);
    }
}

// ---------- scatter into bucket-contiguous chunks (packed pairs) ----------
// packed: bits 0..23 = src row, bits 24..31 = dest low 8
__global__ __launch_bounds__(512) void k_scatter(const int* __restrict__ row,
                                                 const int* __restrict__ col,
                                                 int* __restrict__ gcursor,
                                                 int* __restrict__ pairs,
                                                 int E, int NB) {
    __shared__ int2 stage[TILE];         // 64 KB
    __shared__ int lcnt[512];
    __shared__ int lex[512];
    __shared__ int gbase[512];
    int t = threadIdx.x, tile = blockIdx.x;
    int base = tile * TILE;
    int cnt = min(TILE, E - base);

    lcnt[t] = 0;
    __syncthreads();
    for (int i = t; i < cnt; i += 512) atomicAdd(&lcnt[col[base + i] >> 8], 1);
    __syncthreads();

    int myc = lcnt[t];
    lex[t] = myc;
    __syncthreads();
    for (int off = 1; off < 512; off <<= 1) {
        int u = (t >= off) ? lex[t - off] : 0;
        __syncthreads();
        lex[t] += u;
        __syncthreads();
    }
    int ex = lex[t] - myc;
    __syncthreads();
    lex[t] = ex;
    lcnt[t] = ex;                         // local cursor
    if (t < NB && myc > 0) gbase[t] = atomicAdd(&gcursor[t], myc);
    __syncthreads();

    for (int i = t; i < cnt; i += 512) {
        int r = row[base + i], c = col[base + i];
        int lpos = atomicAdd(&lcnt[c >> 8], 1);
        stage[lpos] = make_int2(r, c);
    }
    __syncthreads();

    for (int i = t; i < cnt; i += 512) {
        int2 p = stage[i];
        int b = p.y >> 8;
        pairs[gbase[b] + (i - lex[b])] = p.x | ((p.y & 255) << 24);
    }
}

// ---------- per-bucket final sort by dest; x8-padded esrc segments; deg ----------
__global__ __launch_bounds__(512) void k_bucket(const int* __restrict__ pairs,
                                                const int* __restrict__ rawBase,
                                                const int* __restrict__ padBase,
                                                int* __restrict__ rowptr,
                                                int* __restrict__ deg,
                                                int* __restrict__ esrc,
                                                int N, int NB) {
    __shared__ int dcnt[256];
    __shared__ int sr[256], sp[256];
    __shared__ int cur[256];
    __shared__ int outbuf[BCAP];         // 28 KB
    int t = threadIdx.x, b = blockIdx.x;
    int d0 = b << 8;
    int nd = min(256, N - d0);
    int bstart = rawBase[b];
    int cnt = rawBase[b + 1] - bstart;
    int pstart = padBase[b];

    if (t < 256) dcnt[t] = 0;
    __syncthreads();
    for (int i = t; i < cnt; i += 512) {
        unsigned p = (unsigned)pairs[bstart + i];
        atomicAdd(&dcnt[p >> 24], 1);
    }
    __syncthreads();

    int myc = 0, myp = 0;
    if (t < 256) {
        myc = dcnt[t];
        myp = (myc + 7) & ~7;
        sr[t] = myc; sp[t] = myp;
    }
    __syncthreads();
    for (int off = 1; off < 256; off <<= 1) {
        int a = 0, c2 = 0;
        if (t < 256 && t >= off) { a = sr[t - off]; c2 = sp[t - off]; }
        __syncthreads();
        if (t < 256) { sr[t] += a; sp[t] += c2; }
        __syncthreads();
    }
    if (t < 256) {
        int pex = sp[t] - myp;
        cur[t] = pex;
        if (t < nd) {
            rowptr[d0 + t] = pstart + pex;
            deg[d0 + t] = myc;            // degree for free
        }
    }
    __syncthreads();
    int pcnt = sp[255];

    if (pcnt <= BCAP) {
        for (int i = t; i < cnt; i += 512) {
            unsigned p = (unsigned)pairs[bstart + i];
            int lpos = atomicAdd(&cur[p >> 24], 1);
            outbuf[lpos] = (int)(p & 0xFFFFFF);
        }
        __syncthreads();
        if (t < 256) {
            int pex = sp[t] - myp;
            for (int j = myc; j < myp; ++j) outbuf[pex + j] = N;   // sentinel pad
        }
        __syncthreads();
        for (int i = t; i < pcnt; i += 512) esrc[pstart + i] = outbuf[i];
    } else {
        for (int i = t; i < cnt; i += 512) {
            unsigned p = (unsigned)pairs[bstart + i];
            int lpos = atomicAdd(&cur[p >> 24], 1);
            esrc[pstart + lpos] = (int)(p & 0xFFFFFF);
        }
        __syncthreads();
        if (t < 256) {
            int pex = sp[t] - myp;
            for (int j = myc; j < myp; ++j) esrc[pstart + pex + j] = N;
        }
    }
}

// ---------- GEMM1 via MFMA: h1' = (x@W1)*dinv, hi/lo fp16 split ----------
__global__ __launch_bounds__(256) void k_gemm1m(const float* __restrict__ x,
                                                const _Float16* __restrict__ W1th,
                                                const _Float16* __restrict__ W1tl,
                                                const int* __restrict__ deg,
                                                __half* __restrict__ h1, int N) {
    __shared__ alignas(16) _Float16 Wh[H1 * WTS];   // 16.5 KB
    __shared__ alignas(16) _Float16 Wl[H1 * WTS];   // 16.5 KB
    int t = threadIdx.x;

    {   // stage both planes: 8448 halves = 1056 uint4 each
        const uint4* sh = (const uint4*)W1th;
        const uint4* sl = (const uint4*)W1tl;
        uint4* dh = (uint4*)Wh;
        uint4* dl = (uint4*)Wl;
        for (int i = t; i < (H1 * WTS) / 8; i += 256) { dh[i] = sh[i]; dl[i] = sl[i]; }
    }

    int wv = t >> 6, l = t & 63;
    int col = l & 15;             // node within 16-tile (and A-row lane index)
    int krow = l >> 4;            // 0..3
    int node = blockIdx.x * 64 + wv * 16 + col;
    int nodec = min(node, N - 1);

    // B fragments from x: lane holds x[node][kt*16 + krow*4 + 0..3]
    half4_t bh[8], bl[8];
    const float4* xr = (const float4*)(x + (size_t)nodec * FIN);
#pragma unroll
    for (int kt = 0; kt < 8; ++kt) {
        float4 v = xr[kt * 4 + krow];
        half4_t hi, lo;
        hi[0] = (_Float16)v.x; lo[0] = (_Float16)(v.x - (float)hi[0]);
        hi[1] = (_Float16)v.y; lo[1] = (_Float16)(v.y - (float)hi[1]);
        hi[2] = (_Float16)v.z; lo[2] = (_Float16)(v.z - (float)hi[2]);
        hi[3] = (_Float16)v.w; lo[3] = (_Float16)(v.w - (float)hi[3]);
        bh[kt] = hi; bl[kt] = lo;
    }
    float dcv = rsqrtf((float)deg[nodec] + 1.0f);
    __syncthreads();

    float4_t acc[4];
#pragma unroll
    for (int ot = 0; ot < 4; ++ot) acc[ot] = (float4_t){0.f, 0.f, 0.f, 0.f};

#pragma unroll
    for (int kt = 0; kt < 8; ++kt) {
#pragma unroll
        for (int ot = 0; ot < 4; ++ot) {
            int aoff = ((ot * 16 + col) * WTS + kt * 16 + krow * 4) >> 2;  // half4 units
            half4_t ah = ((const half4_t*)Wh)[aoff];
            half4_t al = ((const half4_t*)Wl)[aoff];
            acc[ot] = __builtin_amdgcn_mfma_f32_16x16x16f16(ah, bh[kt], acc[ot], 0, 0, 0);
            acc[ot] = __builtin_amdgcn_mfma_f32_16x16x16f16(ah, bl[kt], acc[ot], 0, 0, 0);
            acc[ot] = __builtin_amdgcn_mfma_f32_16x16x16f16(al, bh[kt], acc[ot], 0, 0, 0);
        }
    }

    if (node < N) {
#pragma unroll
        for (int ot = 0; ot < 4; ++ot) {
            union { __half h[4]; uint2 u; } pk;
#pragma unroll
            for (int r = 0; r < 4; ++r) pk.h[r] = __float2half_rn(acc[ot][r] * dcv);
            *(uint2*)&h1[(size_t)node * H1 + ot * 16 + krow * 4] = pk.u;
        }
    }
}

// ---------- fused agg1 + bias + ReLU + GEMM2(MFMA) per 64-node block ----------
// 512 threads = 8 waves. Aggregation: EXACT R17 shape (half h takes edges
// i+8h..i+8h+7 via two int4 loads, 8 gathers in flight; proven 54 us).
// Epilogue writes hs as hi/lo fp16 planes. GEMM2: 12 16x16 MFMA tiles over
// 8 waves, 3 mfma per k-step (hi/lo, fp32-grade) — replaces ~8K VALU cyc
// of scalar GEMM2 per block with ~150 MFMA + ~200 LDS instr.
__global__ __launch_bounds__(512) void k_agg1mm(const int* __restrict__ rowptr,
                                                const int* __restrict__ deg,
                                                const int* __restrict__ esrc,
                                                const __half* __restrict__ h1,
                                                const float* __restrict__ b1,
                                                const _Float16* __restrict__ W2th,
                                                const _Float16* __restrict__ W2tl,
                                                __half* __restrict__ g, int N) {
    __shared__ alignas(16) _Float16 hsh[64][W2TS];   // 9.2 KB
    __shared__ alignas(16) _Float16 hsl[64][W2TS];   // 9.2 KB
    __shared__ alignas(16) _Float16 Wth[48][W2TS];   // 6.9 KB
    __shared__ alignas(16) _Float16 Wtl[48][W2TS];   // 6.9 KB
    __shared__ float sdc[64];
    int t = threadIdx.x;
    int node0 = blockIdx.x * 64;

    {   // stage W2t planes: 432 uint4 each
        const uint4* sh = (const uint4*)W2th;
        const uint4* sl = (const uint4*)W2tl;
        uint4* dh = (uint4*)Wth;
        uint4* dl = (uint4*)Wtl;
        for (int i = t; i < 432; i += 512) { dh[i] = sh[i]; dl[i] = sl[i]; }
    }

    int wv = t >> 6, lane = t & 63;
    int half = lane >> 5;                // edge-octet selector
    int f = lane & 31;                   // feature-pair index
    float2 b1v = *(const float2*)&b1[2 * f];
    const __half2* hp = (const __half2*)h1;

    // aggregation: 8 nodes per wave, sequential (EXACT R17 loop)
#pragma unroll 1
    for (int j = 0; j < 8; ++j) {
        int r = wv * 8 + j;
        int node = node0 + r;
        if (node >= N) {
            if (lane < 32) { *(unsigned*)&hsh[r][2 * f] = 0u; *(unsigned*)&hsl[r][2 * f] = 0u; }
            if (lane == 0) sdc[r] = 0.f;
            continue;
        }
        int start = rowptr[node], d = deg[node];
        int d8 = (d + 7) & ~7;
        float dc = rsqrtf((float)d + 1.0f);
        float ax = 0.f, ay = 0.f;
        int i = 0;
#pragma unroll 1
        for (; i + 16 <= d8; i += 16) {
            int b0 = start + i + half * 8;
            int4 sA = *(const int4*)&esrc[b0];
            int4 sB = *(const int4*)&esrc[b0 + 4];
            float2 v0 = __half22float2(hp[sA.x * 32 + f]);
            float2 v1 = __half22float2(hp[sA.y * 32 + f]);
            float2 v2 = __half22float2(hp[sA.z * 32 + f]);
            float2 v3 = __half22float2(hp[sA.w * 32 + f]);
            float2 v4 = __half22float2(hp[sB.x * 32 + f]);
            float2 v5 = __half22float2(hp[sB.y * 32 + f]);
            float2 v6 = __half22float2(hp[sB.z * 32 + f]);
            float2 v7 = __half22float2(hp[sB.w * 32 + f]);
            ax += ((v0.x + v1.x) + (v2.x + v3.x)) + ((v4.x + v5.x) + (v6.x + v7.x));
            ay += ((v0.y + v1.y) + (v2.y + v3.y)) + ((v4.y + v5.y) + (v6.y + v7.y));
        }
        if (i < d8) {                    // one 8-edge chunk: 4 per half
            int4 s = *(const int4*)&esrc[start + i + half * 4];
            float2 v0 = __half22float2(hp[s.x * 32 + f]);
            float2 v1 = __half22float2(hp[s.y * 32 + f]);
            float2 v2 = __half22float2(hp[s.z * 32 + f]);
            float2 v3 = __half22float2(hp[s.w * 32 + f]);
            ax += (v0.x + v1.x) + (v2.x + v3.x);
            ay += (v0.y + v1.y) + (v2.y + v3.y);
        }
        // cross-half reduce (both halves end with full sum)
        ax += __shfl(ax, lane ^ 32);
        ay += __shfl(ay, lane ^ 32);
        // self-loop (h1' already has one dinv factor) + bias + ReLU
        float2 sv = __half22float2(hp[node * 32 + f]);
        ax = fmaxf(fmaf(dc, ax + sv.x, b1v.x), 0.f);
        ay = fmaxf(fmaf(dc, ay + sv.y, b1v.y), 0.f);
        if (lane < 32) {
            // hi/lo fp16 split (exact): hs = hi + lo to ~2^-22
            _Float16 axh = (_Float16)ax;
            _Float16 ayh = (_Float16)ay;
            _Float16 axl = (_Float16)(ax - (float)axh);
            _Float16 ayl = (_Float16)(ay - (float)ayh);
            union { _Float16 h[2]; unsigned u; } ph, pl;
            ph.h[0] = axh; ph.h[1] = ayh;
            pl.h[0] = axl; pl.h[1] = ayl;
            *(unsigned*)&hsh[r][2 * f] = ph.u;
            *(unsigned*)&hsl[r][2 * f] = pl.u;
        }
        if (lane == 0) sdc[r] = dc;
    }
    __syncthreads();

    // GEMM2 via MFMA: D[64 nodes][48 cols] = hs(h/l) x W2t(h/l); 12 tiles / 8 waves.
    // Fragment layout identical to k_gemm1m (verified): A row = lane&15 at read,
    // D row = (lane>>4)*4+r at write, D col = lane&15.
    int l15 = lane & 15, kg = (lane >> 4) * 4;
#pragma unroll 1
    for (int tile = wv; tile < 12; tile += 8) {
        int mt = tile & 3, nt = tile >> 2;
        int arow = mt * 16 + l15;
        int bcol = nt * 16 + l15;
        float4_t acc = (float4_t){0.f, 0.f, 0.f, 0.f};
#pragma unroll
        for (int kt = 0; kt < 4; ++kt) {
            int ko = kt * 16 + kg;
            half4_t ah = *(const half4_t*)&hsh[arow][ko];
            half4_t al = *(const half4_t*)&hsl[arow][ko];
            half4_t bh = *(const half4_t*)&Wth[bcol][ko];
            half4_t bl = *(const half4_t*)&Wtl[bcol][ko];
            acc = __builtin_amdgcn_mfma_f32_16x16x16f16(ah, bh, acc, 0, 0, 0);
            acc = __builtin_amdgcn_mfma_f32_16x16x16f16(ah, bl, acc, 0, 0, 0);
            acc = __builtin_amdgcn_mfma_f32_16x16x16f16(al, bh, acc, 0, 0, 0);
        }
        int colo = nt * 16 + l15;
        if (colo < C2) {                 // cols 40-47 are zero; 48-63 untouched
#pragma unroll
            for (int r2 = 0; r2 < 4; ++r2) {
                int nd = mt * 16 + (lane >> 4) * 4 + r2;
                int node = node0 + nd;
                if (node < N) {
                    g[(size_t)node * GP + colo] = __float2half_rn(acc[r2] * sdc[nd]);
                }
            }
        }
    }
}

// ---------- agg2: wave per node, pre-scaled g' rows, 16-edge iterations (EXACT R17) ----------
__global__ __launch_bounds__(256) void k_agg2(const int* __restrict__ rowptr,
                                              const int* __restrict__ deg,
                                              const int* __restrict__ esrc,
                                              const __half* __restrict__ g,
                                              const float* __restrict__ b2,
                                              float* __restrict__ out, int N) {
    int w = (int)((blockIdx.x * blockDim.x + threadIdx.x) >> 6);
    int lane = threadIdx.x & 63;
    if (w >= N) return;
    int half = lane >> 5;
    int f = lane & 31;                   // feature-pair; active f<20
    bool act = f < 20;
    const __half2* gp = (const __half2*)g;

    int start = rowptr[w], d = deg[w];
    int d8 = (d + 7) & ~7;
    float dc = rsqrtf((float)d + 1.0f);
    float ax = 0.f, ay = 0.f;
    int i = 0;
#pragma unroll 1
    for (; i + 16 <= d8; i += 16) {
        int b0 = start + i + half * 8;
        int4 sA = *(const int4*)&esrc[b0];
        int4 sB = *(const int4*)&esrc[b0 + 4];
        float2 v0 = __half22float2(gp[sA.x * 32 + f]);
        float2 v1 = __half22float2(gp[sA.y * 32 + f]);
        float2 v2 = __half22float2(gp[sA.z * 32 + f]);
        float2 v3 = __half22float2(gp[sA.w * 32 + f]);
        float2 v4 = __half22float2(gp[sB.x * 32 + f]);
        float2 v5 = __half22float2(gp[sB.y * 32 + f]);
        float2 v6 = __half22float2(gp[sB.z * 32 + f]);
        float2 v7 = __half22float2(gp[sB.w * 32 + f]);
        ax += ((v0.x + v1.x) + (v2.x + v3.x)) + ((v4.x + v5.x) + (v6.x + v7.x));
        ay += ((v0.y + v1.y) + (v2.y + v3.y)) + ((v4.y + v5.y) + (v6.y + v7.y));
    }
    if (i < d8) {
        int4 s = *(const int4*)&esrc[start + i + half * 4];
        float2 v0 = __half22float2(gp[s.x * 32 + f]);
        float2 v1 = __half22float2(gp[s.y * 32 + f]);
        float2 v2 = __half22float2(gp[s.z * 32 + f]);
        float2 v3 = __half22float2(gp[s.w * 32 + f]);
        ax += (v0.x + v1.x) + (v2.x + v3.x);
        ay += (v0.y + v1.y) + (v2.y + v3.y);
    }
    ax += __shfl(ax, lane ^ 32);
    ay += __shfl(ay, lane ^ 32);
    if (lane < 32 && act) {
        float2 b2v = *(const float2*)&b2[2 * f];
        float2 sv = __half22float2(gp[w * 32 + f]);
        float2 o;
        o.x = fmaf(dc, ax + sv.x, b2v.x);
        o.y = fmaf(dc, ay + sv.y, b2v.y);
        *(float2*)&out[(size_t)w * C2 + 2 * f] = o;
    }
}

extern "C" void kernel_launch(void* const* d_in, const int* in_sizes, int n_in,
                              void* d_out, int out_size, void* d_ws, size_t ws_size,
                              hipStream_t stream) {
    const float* x   = (const float*)d_in[0];
    const int*   ei  = (const int*)d_in[1];
    const float* W1  = (const float*)d_in[2];
    const float* b1  = (const float*)d_in[3];
    const float* W2  = (const float*)d_in[4];
    const float* b2  = (const float*)d_in[5];
    float* out = (float*)d_out;

    const int N = in_sizes[0] / FIN;       // 100000
    const int E = in_sizes[1] / 2;         // 1600000
    const int* row = ei;
    const int* col = ei + E;

    const int NB = (N + 255) >> 8;         // 391 buckets
    const int T  = (E + TILE - 1) / TILE;  // 196 tiles
    const int EP = E + NB * 2048 + 1024;   // padded esrc capacity (x8 pad)

    // workspace layout
    char* ws = (char*)d_ws;
    size_t off = 0;
    int*    bucketCnt = (int*)(ws + off);    off += (size_t)NB * 4;
    int*    rawBase   = (int*)(ws + off);    off += (size_t)(NB + 1) * 4;
    int*    padBase   = (int*)(ws + off);    off += (size_t)(NB + 1) * 4;
    int*    gcursor   = (int*)(ws + off);    off += (size_t)NB * 4;
    int*    deg       = (int*)(ws + off);    off += (size_t)N * 4;
    int*    rowptr    = (int*)(ws + off);    off += (size_t)N * 4;
    int*    pairs     = (int*)(ws + off);    off += (size_t)E * 4;
    off = (off + 15) & ~(size_t)15;
    int*    esrc      = (int*)(ws + off);    off += (size_t)EP * 4;
    off = (off + 15) & ~(size_t)15;
    _Float16* W1th    = (_Float16*)(ws + off); off += (size_t)H1 * WTS * 2;
    off = (off + 15) & ~(size_t)15;
    _Float16* W1tl    = (_Float16*)(ws + off); off += (size_t)H1 * WTS * 2;
    off = (off + 15) & ~(size_t)15;
    _Float16* W2th    = (_Float16*)(ws + off); off += (size_t)48 * W2TS * 2;
    off = (off + 15) & ~(size_t)15;
    _Float16* W2tl    = (_Float16*)(ws + off); off += (size_t)48 * W2TS * 2;
    off = (off + 15) & ~(size_t)15;
    __half* h1        = (__half*)(ws + off); off += (size_t)(N + 1) * H1 * 2;
    off = (off + 15) & ~(size_t)15;
    __half* g         = (__half*)(ws + off); off += (size_t)(N + 1) * GP * 2;

    hipMemsetAsync(bucketCnt, 0, (size_t)NB * 4, stream);

    int gblocks = (N + 63) / 64;           // 1563

    // CSR build: bucket histogram -> scan (+W1t/W2t planes) -> chunk-claim
    // scatter -> bucket sort (emits deg for free)
    k_hist<<<T, 256, 0, stream>>>(col, E, bucketCnt, NB);
    k_scan<<<1, 512, 0, stream>>>(bucketCnt, rawBase, padBase, gcursor, h1, g,
                                  W1, W1th, W1tl, W2, W2th, W2tl, NB, N);
    k_scatter<<<T, 512, 0, stream>>>(row, col, gcursor, pairs, E, NB);
    k_bucket<<<NB, 512, 0, stream>>>(pairs, rawBase, padBase, rowptr, deg, esrc, N, NB);

    // GEMM1 via MFMA, writes h1' = (x@W1)*dinv (needs deg => after k_bucket)
    k_gemm1m<<<gblocks, 256, 0, stream>>>(x, W1th, W1tl, deg, h1, N);

    // layer 1 aggregation + bias + ReLU + GEMM2 via MFMA (fused), writes g' = h2*dinv
    k_agg1mm<<<gblocks, 512, 0, stream>>>(rowptr, deg, esrc, h1, b1, W2th, W2tl, g, N);

    // layer 2 aggregation + bias
    k_agg2<<<((size_t)N * 64 + 255) / 256, 256, 0, stream>>>(rowptr, deg, esrc, g, b2, out, N);
}